// Round 1
// baseline (1334.106 us; speedup 1.0000x reference)
//
#include <hip/hip_runtime.h>
#include <math.h>

#define NUM_I 100
#define NZ    16
#define NCAND (NUM_I * NZ)
#define F32_EPS 1.1920928955078125e-07f

// force a wave-uniform float into an SGPR
static __device__ __forceinline__ float rfl_f(float v) {
    return __int_as_float(__builtin_amdgcn_readfirstlane(__float_as_int(v)));
}

// ---------------- K1: per-block min/max partials ----------------
__global__ __launch_bounds__(256) void k_minmax(const float* __restrict__ x, int n4,
                                                float* __restrict__ pmin,
                                                float* __restrict__ pmax) {
    int tid = blockIdx.x * blockDim.x + threadIdx.x;
    int stride = gridDim.x * blockDim.x;
    const float4* x4 = (const float4*)x;
    float lmin = 3.0e38f, lmax = -3.0e38f;
    for (int i = tid; i < n4; i += stride) {
        float4 v = x4[i];
        lmin = fminf(lmin, fminf(fminf(v.x, v.y), fminf(v.z, v.w)));
        lmax = fmaxf(lmax, fmaxf(fmaxf(v.x, v.y), fmaxf(v.z, v.w)));
    }
    #pragma unroll
    for (int off = 32; off > 0; off >>= 1) {
        lmin = fminf(lmin, __shfl_xor(lmin, off));
        lmax = fmaxf(lmax, __shfl_xor(lmax, off));
    }
    __shared__ float smin[4], smax[4];
    int w = threadIdx.x >> 6;
    if ((threadIdx.x & 63) == 0) { smin[w] = lmin; smax[w] = lmax; }
    __syncthreads();
    if (threadIdx.x == 0) {
        pmin[blockIdx.x] = fminf(fminf(smin[0], smin[1]), fminf(smin[2], smin[3]));
        pmax[blockIdx.x] = fmaxf(fmaxf(smax[0], smax[1]), fmaxf(smax[2], smax[3]));
    }
}

// ---------------- K2: final min/max + candidate params (+ zero scores) ----------------
__global__ __launch_bounds__(256) void k_params(const float* __restrict__ pmin,
                                                const float* __restrict__ pmax, int nb,
                                                float4* __restrict__ params,
                                                float2* __restrict__ ranges,
                                                double* __restrict__ score,
                                                float* __restrict__ mm) {
#pragma clang fp contract(off)
    __shared__ float smin[256], smax[256];
    float lmin = 3.0e38f, lmax = -3.0e38f;
    for (int i = threadIdx.x; i < nb; i += 256) {
        lmin = fminf(lmin, pmin[i]);
        lmax = fmaxf(lmax, pmax[i]);
    }
    smin[threadIdx.x] = lmin; smax[threadIdx.x] = lmax;
    __syncthreads();
    for (int s = 128; s > 0; s >>= 1) {
        if (threadIdx.x < s) {
            smin[threadIdx.x] = fminf(smin[threadIdx.x], smin[threadIdx.x + s]);
            smax[threadIdx.x] = fmaxf(smax[threadIdx.x], smax[threadIdx.x + s]);
        }
        __syncthreads();
    }
    float x_min = smin[0], x_max = smax[0];
    if (threadIdx.x == 0) { mm[0] = x_min; mm[1] = x_max; }

    float xrange = x_max - x_min;
    float step = xrange / 100.0f;            // xrange / NUM (fp32, no contraction)
    for (int c = threadIdx.x; c < NCAND; c += 256) {
        int ii = c >> 4;                      // 0..99  -> i = ii+1
        int z  = c & 15;
        float fi = (float)(ii + 1);
        float tmp_max   = step * fi;
        float tmp_delta = tmp_max / 15.0f;
        float t = (float)z * tmp_delta;       // zps * tmp_delta, rounded separately
        float new_min = fmaxf(-t, x_min);
        float new_max = fminf(tmp_max - t, x_max);
        float min_neg = fminf(new_min, 0.0f);
        float max_pos = fmaxf(new_max, 0.0f);
        float scale = fmaxf((max_pos - min_neg) / 15.0f, F32_EPS);
        float zp = 0.0f - rintf(min_neg / scale);   // QMIN - round(min_neg/scale)
        zp = fminf(fmaxf(zp, 0.0f), 15.0f);
        float inv = (float)(1.0 / (double)scale);   // correctly-rounded fp32 reciprocal
        params[c] = make_float4(scale, inv, 0.0f - zp, 15.0f - zp);
        ranges[c] = make_float2(new_min, new_max);
        score[c]  = 0.0;
    }
}

// ---------------- K3: the heavy scorer ----------------
// Each thread owns 16 elements in registers; loops over all 1600 candidates.
__global__ __launch_bounds__(256) void k_score(const float* __restrict__ x, int n4,
                                               const float4* __restrict__ params,
                                               double* __restrict__ score) {
    const int tid = blockIdx.x * 256 + threadIdx.x;
    const int T = gridDim.x * 256;
    const float4* x4 = (const float4*)x;
    float xs[16];
    #pragma unroll
    for (int k = 0; k < 4; k++) {
        int i4 = tid + k * T;
        float4 v;
        if (i4 < n4) v = x4[i4];
        else { v.x = 0.0f; v.y = 0.0f; v.z = 0.0f; v.w = 0.0f; }  // 0 quantizes exactly -> score-neutral
        xs[4*k+0] = v.x; xs[4*k+1] = v.y; xs[4*k+2] = v.z; xs[4*k+3] = v.w;
    }

    // rotate candidate order per block to spread atomics on each score cell over time
    int c = (int)((blockIdx.x * 37u) % NCAND);
    for (int k = 0; k < NCAND; k++) {
        float4 p = params[c];
        float s   = rfl_f(p.x);
        float inv = rfl_f(p.y);
        float lo  = rfl_f(p.z);
        float hi  = rfl_f(p.w);
        float acc = 0.0f;
        #pragma unroll
        for (int e = 0; e < 16; e++) {
            float r = rintf(xs[e] * inv);         // round-half-even == jnp.round
            r = fminf(fmaxf(r, lo), hi);          // v_med3: clamp(round, -zp, 15-zp)
            float d = fmaf(r, s, -xs[e]);         // xq - x
            acc = fmaf(d, d, acc);
        }
        #pragma unroll
        for (int off = 32; off > 0; off >>= 1)
            acc += __shfl_xor(acc, off);
        if ((threadIdx.x & 63) == 0)
            atomicAdd(&score[c], (double)acc);
        c++; if (c >= NCAND) c -= NCAND;
    }
}

// ---------------- K4: argmin scan with exact reference tie-break semantics ----------------
__global__ void k_final(const double* __restrict__ score,
                        const float2* __restrict__ ranges,
                        const float* __restrict__ mm,
                        float* __restrict__ out, int n) {
    if (blockIdx.x == 0 && threadIdx.x == 0) {
        double best = 1.0e10;
        float bmin = mm[0], bmax = mm[1];
        double inv_n = 1.0 / (double)n;
        // flat i-major, z-minor order + strict '<' replicates per-i argmin + strict update
        for (int c = 0; c < NCAND; c++) {
            double sc = score[c] * inv_n;
            if (sc < best) { best = sc; bmin = ranges[c].x; bmax = ranges[c].y; }
        }
        out[0] = bmin;
        out[1] = bmax;
    }
}

extern "C" void kernel_launch(void* const* d_in, const int* in_sizes, int n_in,
                              void* d_out, int out_size, void* d_ws, size_t ws_size,
                              hipStream_t stream) {
    const float* x = (const float*)d_in[0];
    int n  = in_sizes[0];          // 4194304
    int n4 = n / 4;                // 1048576 (n is a multiple of 4)
    float* out = (float*)d_out;

    // workspace layout (16B-aligned head first)
    char* w = (char*)d_ws;
    float4* params = (float4*)w;            w += sizeof(float4) * NCAND;   // 25600
    float2* ranges = (float2*)w;            w += sizeof(float2) * NCAND;   // 12800
    double* score  = (double*)w;            w += sizeof(double) * NCAND;   // 12800
    float*  pmin   = (float*)w;             w += sizeof(float) * 1024;
    float*  pmax   = (float*)w;             w += sizeof(float) * 1024;
    float*  mm     = (float*)w;             w += sizeof(float) * 2;

    const int MMBLOCKS = 1024;
    k_minmax<<<MMBLOCKS, 256, 0, stream>>>(x, n4, pmin, pmax);
    k_params<<<1, 256, 0, stream>>>(pmin, pmax, MMBLOCKS, params, ranges, score, mm);

    int nthreads = (n4 + 3) / 4;                 // 4 float4 per thread
    int blocks = (nthreads + 255) / 256;         // 1024 blocks
    k_score<<<blocks, 256, 0, stream>>>(x, n4, params, score);

    k_final<<<1, 64, 0, stream>>>(score, ranges, mm, out, n);
}